// Round 6
// baseline (1416.272 us; speedup 1.0000x reference)
//
#include <hip/hip_runtime.h>
#include <math.h>

// ---------------------------------------------------------------------------
// GCN-VAE fused pipeline for MI355X.
// R5: fixes R3/R4 crash. Root cause: bucketize emits self-loop pairs, so
// hist already counts them -- but scan still added +1 per node. offsets[N]
// became E+2N while esrc holds E+N -> fill wrote ~200KB past esrc, trashing
// cursor/offs mid-run -> wild writes -> abort. Fix: deg = count[i] directly.
// Also: hist/fill drain own XCD's bucket first then sweep all 8 (correct
// even if some XCC_ID never appears).
// ---------------------------------------------------------------------------

__device__ inline float bf2f_lo(unsigned int v) {
    return __uint_as_float(v << 16);
}
__device__ inline float bf2f_hi(unsigned int v) {
    return __uint_as_float(v & 0xFFFF0000u);
}
__device__ inline unsigned short f2bf(float f) {
    unsigned int u = __float_as_uint(f);
    return (unsigned short)((u + 0x7FFFu + ((u >> 16) & 1u)) >> 16);
}
__device__ inline unsigned int get_xcd() {
    unsigned int x;
    asm volatile("s_getreg_b32 %0, hwreg(HW_REG_XCC_ID)" : "=s"(x));
    return x & 7u;
}

__global__ void zero_kernel(int* __restrict__ p, int n) {
    int i = blockIdx.x * blockDim.x + threadIdx.x;
    if (i < n) p[i] = 0;
}

// Partition edges (+self-loops) into 8 dst-range buckets. Reads the edge
// stream ONCE; LDS-staged per-block counts -> one global atomic per bucket
// per block-iteration; packed (dst,src) uint2 writes.
__global__ __launch_bounds__(256) void bucketize_kernel(
    const int* __restrict__ src, const int* __restrict__ dst, int E, int N,
    int S, uint2* __restrict__ pairs, int cap, int* __restrict__ gcnt) {
    __shared__ int lcnt[8];
    __shared__ int lbase[8];
    int tid = threadIdx.x;
    int total = E + N;
    for (int base = blockIdx.x * 256; base < total; base += gridDim.x * 256) {
        if (tid < 8) lcnt[tid] = 0;
        __syncthreads();
        int idx = base + tid;
        int d = 0, s = 0, b = 0, my = 0;
        bool valid = idx < total;
        if (valid) {
            if (idx < E) { d = dst[idx]; s = src[idx]; }
            else         { d = idx - E; s = d; }
            b = (int)((unsigned)d / (unsigned)S);
            my = atomicAdd(&lcnt[b], 1);
        }
        __syncthreads();
        if (tid < 8) lbase[tid] = atomicAdd(&gcnt[tid], lcnt[tid]);
        __syncthreads();
        if (valid) {
            int pos = lbase[b] + my;
            if (pos < cap)
                pairs[(size_t)b * cap + pos] =
                    make_uint2((unsigned)d, (unsigned)s);
        }
        __syncthreads();
    }
}

// Histogram: own XCD's bucket first (L2-local atomics), then sweep all
// buckets via ticket queues so every bucket is drained no matter how
// blocks map to XCDs.
__global__ __launch_bounds__(256) void hist_bucket_kernel(
    const uint2* __restrict__ pairs, int cap, const int* __restrict__ gcnt,
    int* __restrict__ tq, int* __restrict__ count) {
    unsigned int xcd = get_xcd();
    __shared__ int sbase;
    int tid = threadIdx.x;
    for (int k = 0; k < 8; k++) {
        int b = (int)((xcd + k) & 7u);
        int sz = gcnt[b]; if (sz > cap) sz = cap;
        const uint2* bp = pairs + (size_t)b * cap;
        for (;;) {
            if (tid == 0) sbase = atomicAdd(&tq[b], 1);
            __syncthreads();
            int base = sbase * 2048;
            bool done = base >= sz;
            __syncthreads();
            if (done) break;
            int lim = base + 2048; if (lim > sz) lim = sz;
            for (int i = base + tid; i < lim; i += 256)
                atomicAdd(&count[bp[i].x], 1);
        }
    }
}

// --- 3-stage parallel scan over deg = count[i] (self-loop already counted) --
__global__ __launch_bounds__(256) void block_sum_kernel(
    const int* __restrict__ count, int N, int* __restrict__ blockSums) {
    int base = blockIdx.x * 1024;
    int s = 0;
#pragma unroll
    for (int j = 0; j < 4; j++) {
        int i = base + j * 256 + threadIdx.x;
        if (i < N) s += count[i];
    }
#pragma unroll
    for (int off = 32; off; off >>= 1) s += __shfl_down(s, off, 64);
    __shared__ int ws[4];
    if ((threadIdx.x & 63) == 0) ws[threadIdx.x >> 6] = s;
    __syncthreads();
    if (threadIdx.x == 0)
        blockSums[blockIdx.x] = ws[0] + ws[1] + ws[2] + ws[3];
}

__global__ __launch_bounds__(256) void scan_sums_kernel(
    const int* __restrict__ blockSums, int nb, int* __restrict__ blockOffs,
    int* __restrict__ offsets, int N) {
    __shared__ int lds[256];
    int tid = threadIdx.x;
    int v = (tid < nb) ? blockSums[tid] : 0;
    lds[tid] = v;
    __syncthreads();
    for (int off = 1; off < 256; off <<= 1) {
        int u = (tid >= off) ? lds[tid - off] : 0;
        __syncthreads();
        lds[tid] += u;
        __syncthreads();
    }
    if (tid < nb) blockOffs[tid] = lds[tid] - v;
    if (tid == 255) offsets[N] = lds[255];
}

__global__ __launch_bounds__(256) void scan_emit_kernel(
    const int* __restrict__ count, const int* __restrict__ blockOffs, int N,
    int* __restrict__ offsets, int* __restrict__ cursor,
    float* __restrict__ dinv) {
    __shared__ int lds[1024];
    __shared__ int tsum[256];
    int tid = threadIdx.x;
    int base = blockIdx.x * 1024;
#pragma unroll
    for (int j = 0; j < 4; j++) {
        int i = base + j * 256 + tid;
        lds[j * 256 + tid] = (i < N) ? count[i] : 0;
    }
    __syncthreads();
    int4 q = ((const int4*)lds)[tid];
    int s = q.x + q.y + q.z + q.w;
    tsum[tid] = s;
    __syncthreads();
    for (int off = 1; off < 256; off <<= 1) {
        int u = (tid >= off) ? tsum[tid - off] : 0;
        __syncthreads();
        tsum[tid] += u;
        __syncthreads();
    }
    int run = blockOffs[blockIdx.x] + ((tid > 0) ? tsum[tid - 1] : 0);
    int4 e;
    e.x = run;
    e.y = run + q.x;
    e.z = run + q.x + q.y;
    e.w = run + q.x + q.y + q.z;
    __syncthreads();
    ((int4*)lds)[tid] = e;
    __syncthreads();
#pragma unroll
    for (int j = 0; j < 4; j++) {
        int i = base + j * 256 + tid;
        if (i < N) {
            int o = lds[j * 256 + tid];
            offsets[i] = o;
            cursor[i] = o;
            dinv[i] = rsqrtf((float)count[i]);   // deg >= 1 (self-loop)
        }
    }
}

// CSR fill: own bucket first, then sweep (same ticket-queue scheme).
__global__ __launch_bounds__(256) void fill_bucket_kernel(
    const uint2* __restrict__ pairs, int cap, const int* __restrict__ gcnt,
    int* __restrict__ tq, int* __restrict__ cursor, int* __restrict__ esrc) {
    unsigned int xcd = get_xcd();
    __shared__ int sbase;
    int tid = threadIdx.x;
    for (int k = 0; k < 8; k++) {
        int b = (int)((xcd + k) & 7u);
        int sz = gcnt[b]; if (sz > cap) sz = cap;
        const uint2* bp = pairs + (size_t)b * cap;
        for (;;) {
            if (tid == 0) sbase = atomicAdd(&tq[b], 1);
            __syncthreads();
            int base = sbase * 2048;
            bool done = base >= sz;
            __syncthreads();
            if (done) break;
            int lim = base + 2048; if (lim > sz) lim = sz;
            for (int i = base + tid; i < lim; i += 256) {
                uint2 p = bp[i];
                int pos = atomicAdd(&cursor[p.x], 1);
                esrc[pos] = (int)p.y;
            }
        }
    }
}

// Tiled matmul: out[N,128] = X[N,K] @ W[K,128], bf16 out. SCALE: multiply
// row r by dinv[r] (prescale for downstream aggregation).
template <int K, bool XBF, bool SCALE>
__global__ __launch_bounds__(256) void matmul_kernel(
    const void* __restrict__ Xv, const float* __restrict__ W,
    const float* __restrict__ dinv, unsigned short* __restrict__ out, int N) {
    const int M = 128;
    __shared__ float ldsW[K][64];
    __shared__ float ldsX[64][K];
    int tid = threadIdx.x;
    int row0 = blockIdx.x * 64;
    int col0 = blockIdx.y * 64;

    for (int i = tid; i < K * 16; i += 256) {
        int k = i >> 4, j4 = i & 15;
        ((float4*)&ldsW[k][0])[j4] =
            *(const float4*)&W[(size_t)k * M + col0 + j4 * 4];
    }
    int maxr = N - row0; if (maxr > 64) maxr = 64;
    if (XBF) {
        const unsigned short* X = (const unsigned short*)Xv;
        for (int i = tid; i < maxr * (K / 8); i += 256) {
            int r = i / (K / 8), c8 = i % (K / 8);
            uint4 u = *(const uint4*)&X[(size_t)(row0 + r) * K + c8 * 8];
            float* dp = &ldsX[r][c8 * 8];
            dp[0] = bf2f_lo(u.x); dp[1] = bf2f_hi(u.x);
            dp[2] = bf2f_lo(u.y); dp[3] = bf2f_hi(u.y);
            dp[4] = bf2f_lo(u.z); dp[5] = bf2f_hi(u.z);
            dp[6] = bf2f_lo(u.w); dp[7] = bf2f_hi(u.w);
        }
    } else {
        const float* X = (const float*)Xv;
        for (int i = tid; i < maxr * (K / 4); i += 256) {
            int r = i / (K / 4), k4 = i % (K / 4);
            ((float4*)&ldsX[r][0])[k4] =
                *(const float4*)&X[(size_t)(row0 + r) * K + k4 * 4];
        }
    }
    __syncthreads();

    int cg = tid & 15, rg = tid >> 4;
    int rbase = rg * 4, cbase = cg * 4;
    float acc[4][4] = {};
    for (int k = 0; k < K; k += 4) {
        float4 xv[4];
#pragma unroll
        for (int r = 0; r < 4; r++)
            xv[r] = *(const float4*)&ldsX[rbase + r][k];
        const float* xp = (const float*)xv;
#pragma unroll
        for (int kk = 0; kk < 4; kk++) {
            float4 wv = *(const float4*)&ldsW[k + kk][cbase];
#pragma unroll
            for (int r = 0; r < 4; r++) {
                float xs = xp[r * 4 + kk];
                acc[r][0] += xs * wv.x;
                acc[r][1] += xs * wv.y;
                acc[r][2] += xs * wv.z;
                acc[r][3] += xs * wv.w;
            }
        }
    }
#pragma unroll
    for (int r = 0; r < 4; r++) {
        int row = row0 + rbase + r;
        if (row < N) {
            float sc = SCALE ? dinv[row] : 1.0f;
            ushort4 o;
            o.x = f2bf(acc[r][0] * sc); o.y = f2bf(acc[r][1] * sc);
            o.z = f2bf(acc[r][2] * sc); o.w = f2bf(acc[r][3] * sc);
            *(ushort4*)&out[(size_t)row * M + col0 + cbase] = o;
        }
    }
}

// Fused VAE head: mean = Ah@Wm+bm, lv = Ah@Wl+bl, z = noise*exp(.5lv)+mean.
// Writes mean/lv/z fp32 (outputs) + zb = dinv*z bf16 (prescaled for W_d1).
__global__ __launch_bounds__(256) void head_kernel(
    const unsigned short* __restrict__ Ah, const float* __restrict__ Wm,
    const float* __restrict__ bm, const float* __restrict__ Wl,
    const float* __restrict__ bl, const float* __restrict__ noise,
    const float* __restrict__ dinv, float* __restrict__ mean,
    float* __restrict__ lv, float* __restrict__ z,
    unsigned short* __restrict__ zb, int N) {
    __shared__ float ldsX[64][128];
    __shared__ float ldsW[128][64];
    int tid = threadIdx.x;
    int row0 = blockIdx.x * 64;
    int maxr = N - row0; if (maxr > 64) maxr = 64;

    for (int i = tid; i < maxr * 16; i += 256) {
        int r = i >> 4, c8 = i & 15;
        uint4 u = *(const uint4*)&Ah[(size_t)(row0 + r) * 128 + c8 * 8];
        float* dp = &ldsX[r][c8 * 8];
        dp[0] = bf2f_lo(u.x); dp[1] = bf2f_hi(u.x);
        dp[2] = bf2f_lo(u.y); dp[3] = bf2f_hi(u.y);
        dp[4] = bf2f_lo(u.z); dp[5] = bf2f_hi(u.z);
        dp[6] = bf2f_lo(u.w); dp[7] = bf2f_hi(u.w);
    }
    for (int i = tid; i < 128 * 16; i += 256) {
        int k = i >> 4, j4 = i & 15;
        ((float4*)&ldsW[k][0])[j4] = ((const float4*)&Wm[(size_t)k * 64])[j4];
    }
    __syncthreads();

    int cg = tid & 15, rg = tid >> 4;
    int rbase = rg * 4, cbase = cg * 4;
    float accM[4][4] = {}, accL[4][4] = {};

    for (int k = 0; k < 128; k += 4) {
        float4 xv[4];
#pragma unroll
        for (int r = 0; r < 4; r++)
            xv[r] = *(const float4*)&ldsX[rbase + r][k];
        const float* xp = (const float*)xv;
#pragma unroll
        for (int kk = 0; kk < 4; kk++) {
            float4 wv = *(const float4*)&ldsW[k + kk][cbase];
#pragma unroll
            for (int r = 0; r < 4; r++) {
                float xs = xp[r * 4 + kk];
                accM[r][0] += xs * wv.x;
                accM[r][1] += xs * wv.y;
                accM[r][2] += xs * wv.z;
                accM[r][3] += xs * wv.w;
            }
        }
    }
    __syncthreads();
    for (int i = tid; i < 128 * 16; i += 256) {
        int k = i >> 4, j4 = i & 15;
        ((float4*)&ldsW[k][0])[j4] = ((const float4*)&Wl[(size_t)k * 64])[j4];
    }
    __syncthreads();
    for (int k = 0; k < 128; k += 4) {
        float4 xv[4];
#pragma unroll
        for (int r = 0; r < 4; r++)
            xv[r] = *(const float4*)&ldsX[rbase + r][k];
        const float* xp = (const float*)xv;
#pragma unroll
        for (int kk = 0; kk < 4; kk++) {
            float4 wv = *(const float4*)&ldsW[k + kk][cbase];
#pragma unroll
            for (int r = 0; r < 4; r++) {
                float xs = xp[r * 4 + kk];
                accL[r][0] += xs * wv.x;
                accL[r][1] += xs * wv.y;
                accL[r][2] += xs * wv.z;
                accL[r][3] += xs * wv.w;
            }
        }
    }

    float4 bmv = *(const float4*)&bm[cbase];
    float4 blv = *(const float4*)&bl[cbase];
#pragma unroll
    for (int r = 0; r < 4; r++) {
        int row = row0 + rbase + r;
        if (row < N) {
            float4 m = make_float4(accM[r][0] + bmv.x, accM[r][1] + bmv.y,
                                   accM[r][2] + bmv.z, accM[r][3] + bmv.w);
            float4 l = make_float4(accL[r][0] + blv.x, accL[r][1] + blv.y,
                                   accL[r][2] + blv.z, accL[r][3] + blv.w);
            float4 nv = *(const float4*)&noise[(size_t)row * 64 + cbase];
            float4 zv = make_float4(nv.x * expf(0.5f * l.x) + m.x,
                                    nv.y * expf(0.5f * l.y) + m.y,
                                    nv.z * expf(0.5f * l.z) + m.z,
                                    nv.w * expf(0.5f * l.w) + m.w);
            *(float4*)&mean[(size_t)row * 64 + cbase] = m;
            *(float4*)&lv[(size_t)row * 64 + cbase] = l;
            *(float4*)&z[(size_t)row * 64 + cbase] = zv;
            float sc = dinv[row];
            ushort4 zq;
            zq.x = f2bf(zv.x * sc); zq.y = f2bf(zv.y * sc);
            zq.z = f2bf(zv.z * sc); zq.w = f2bf(zv.w * sc);
            *(ushort4*)&zb[(size_t)row * 64 + cbase] = zq;
        }
    }
}

// Paired-lane aggregation over dinv-prescaled bf16 rows.
// Wave w -> dst node w. Lanes 0-31 handle even edges, 32-63 odd edges;
// each lane loads 8B (4 cols). Halves combined with shfl_xor(32).
template <bool PRE, bool OUTBF>
__global__ __launch_bounds__(256) void agg_kernel(
    const unsigned short* __restrict__ Y, const int* __restrict__ offsets,
    const int* __restrict__ esrc, const float* __restrict__ dinv,
    const float* __restrict__ bias, void* __restrict__ outv, int N) {
    int gid = blockIdx.x * 256 + threadIdx.x;
    int wid = gid >> 6;
    if (wid >= N) return;
    int lane = threadIdx.x & 63;
    int half = lane >> 5;
    int l32 = lane & 31;
    int beg = __builtin_amdgcn_readfirstlane(offsets[wid]);
    int end = __builtin_amdgcn_readfirstlane(offsets[wid + 1]);

    float ax = 0.f, ay = 0.f, az = 0.f, aw = 0.f;
#define ROW(s) (((const uint2*)(const void*)(Y + (size_t)(s) * 128))[l32])
#define ACC(v)                                                              \
    do {                                                                    \
        ax += bf2f_lo((v).x); ay += bf2f_hi((v).x);                         \
        az += bf2f_lo((v).y); aw += bf2f_hi((v).y);                         \
    } while (0)
    int e = beg;
    for (; e + 8 <= end; e += 8) {
        int i0 = esrc[e + 0], i1 = esrc[e + 1], i2 = esrc[e + 2],
            i3 = esrc[e + 3], i4 = esrc[e + 4], i5 = esrc[e + 5],
            i6 = esrc[e + 6], i7 = esrc[e + 7];
        int sa = half ? i1 : i0;
        int sb = half ? i3 : i2;
        int sc = half ? i5 : i4;
        int sd = half ? i7 : i6;
        uint2 va = ROW(sa), vb = ROW(sb), vc = ROW(sc), vd = ROW(sd);
        ACC(va); ACC(vb); ACC(vc); ACC(vd);
    }
    for (; e + 2 <= end; e += 2) {
        int i0 = esrc[e], i1 = esrc[e + 1];
        int s = half ? i1 : i0;
        uint2 v = ROW(s);
        ACC(v);
    }
    if (e < end && half == 0) {
        uint2 v = ROW(esrc[e]);
        ACC(v);
    }
#undef ROW
#undef ACC
    ax += __shfl_xor(ax, 32);
    ay += __shfl_xor(ay, 32);
    az += __shfl_xor(az, 32);
    aw += __shfl_xor(aw, 32);

    if (half == 0) {
        float dd = dinv[wid];
        float t0 = ax * dd, t1 = ay * dd, t2 = az * dd, t3 = aw * dd;
        if (bias) {
            float4 b4 = *(const float4*)&bias[l32 * 4];
            t0 += b4.x; t1 += b4.y; t2 += b4.z; t3 += b4.w;
        }
        if (PRE) { t0 *= dd; t1 *= dd; t2 *= dd; t3 *= dd; }
        if (OUTBF) {
            uint2 o;
            o.x = (unsigned int)f2bf(t0) | ((unsigned int)f2bf(t1) << 16);
            o.y = (unsigned int)f2bf(t2) | ((unsigned int)f2bf(t3) << 16);
            ((uint2*)outv)[(size_t)wid * 32 + l32] = o;
        } else {
            ((float4*)outv)[(size_t)wid * 32 + l32] =
                make_float4(t0, t1, t2, t3);
        }
    }
}

extern "C" void kernel_launch(void* const* d_in, const int* in_sizes, int n_in,
                              void* d_out, int out_size, void* d_ws,
                              size_t ws_size, hipStream_t stream) {
    const float* feature = (const float*)d_in[0];
    const int*   ei      = (const int*)d_in[1];
    const float* noise   = (const float*)d_in[2];
    const float* W_enc   = (const float*)d_in[3];
    const float* b_enc   = (const float*)d_in[4];
    const float* W_mean  = (const float*)d_in[5];
    const float* b_mean  = (const float*)d_in[6];
    const float* W_lv    = (const float*)d_in[7];
    const float* b_lv    = (const float*)d_in[8];
    const float* W_d1    = (const float*)d_in[9];
    const float* b_d1    = (const float*)d_in[10];
    const float* W_d2    = (const float*)d_in[11];
    const float* b_d2    = (const float*)d_in[12];

    int N = in_sizes[0] / 128;
    int E = in_sizes[1] / 2;
    int S = (N + 7) / 8;                      // dst slice per bucket/XCD

    float* z_out    = (float*)d_out;
    float* mean_out = z_out + (size_t)N * 64;
    float* lv_out   = z_out + (size_t)N * 128;
    float* gout     = z_out + (size_t)N * 192;

    char* ws = (char*)d_ws;
    unsigned short* Ybf = (unsigned short*)ws; ws += (size_t)N * 128 * 2;
    unsigned short* Hbf = (unsigned short*)ws; ws += (size_t)N * 128 * 2;
    unsigned short* Zbf = (unsigned short*)ws; ws += (size_t)N * 64 * 2;
    int*   esrc   = (int*)ws;   ws += (size_t)(E + N) * 4;
    int*   count  = (int*)ws;   ws += (size_t)N * 4;
    int*   ctrl   = (int*)ws;   ws += 32 * 4;  // gcnt[8], tq_hist[8], tq_fill[8]
    int*   offs   = (int*)ws;   ws += (size_t)(N + 1) * 4;
    int*   cursor = (int*)ws;   ws += (size_t)N * 4;
    float* dinv   = (float*)ws; ws += (size_t)N * 4;
    int*   bsums  = (int*)ws;   ws += 256 * 4;
    int*   boffs  = (int*)ws;   ws += 256 * 4;

    // `pairs` ALIASES Ybf+Hbf (CSR build completes before matmuls touch Ybf).
    uint2* pairs = (uint2*)Ybf;
    size_t pairRegion = (size_t)N * 128 * 2 * 2;          // Ybf+Hbf bytes
    int cap = (E + N) / 8 + 32768;
    int capMax = (int)(pairRegion / (8 * sizeof(uint2)));
    if (cap > capMax) cap = capMax;

    int* gcnt = ctrl;
    int* tqh  = ctrl + 8;
    int* tqf  = ctrl + 16;

    const int* src = ei;
    const int* dst = ei + E;

    int nb = (N + 1023) / 1024;

    // ---- CSR build ----
    zero_kernel<<<(N + 32 + 255) / 256, 256, 0, stream>>>(count, N + 32);
    bucketize_kernel<<<2048, 256, 0, stream>>>(src, dst, E, N, S, pairs, cap,
                                               gcnt);
    hist_bucket_kernel<<<2048, 256, 0, stream>>>(pairs, cap, gcnt, tqh, count);
    block_sum_kernel<<<nb, 256, 0, stream>>>(count, N, bsums);
    scan_sums_kernel<<<1, 256, 0, stream>>>(bsums, nb, boffs, offs, N);
    scan_emit_kernel<<<nb, 256, 0, stream>>>(count, boffs, N, offs, cursor,
                                             dinv);
    fill_bucket_kernel<<<2048, 256, 0, stream>>>(pairs, cap, gcnt, tqf,
                                                 cursor, esrc);

    int gx = (N + 63) / 64;
    int aggBlocks = (N + 3) / 4;   // one wave per dst node

    // ---- encoder ----
    matmul_kernel<128, false, true><<<dim3(gx, 2), 256, 0, stream>>>(
        feature, W_enc, dinv, Ybf, N);                       // Y1' = dinv*X@We
    agg_kernel<true, true><<<aggBlocks, 256, 0, stream>>>(
        Ybf, offs, esrc, dinv, b_enc, Hbf, N);               // h' = dinv*h
    agg_kernel<false, true><<<aggBlocks, 256, 0, stream>>>(
        Hbf, offs, esrc, dinv, nullptr, Ybf, N);             // Ah
    head_kernel<<<gx, 256, 0, stream>>>(Ybf, W_mean, b_mean, W_lv, b_lv,
                                        noise, dinv, mean_out, lv_out, z_out,
                                        Zbf, N);             // + zb = dinv*z

    // ---- decoder ----
    matmul_kernel<64, true, false><<<dim3(gx, 2), 256, 0, stream>>>(
        Zbf, W_d1, dinv, Hbf, N);                            // Y2' = dinv*z@Wd1
    agg_kernel<true, true><<<aggBlocks, 256, 0, stream>>>(
        Hbf, offs, esrc, dinv, b_d1, Ybf, N);                // hd' = dinv*hd
    matmul_kernel<128, true, false><<<dim3(gx, 2), 256, 0, stream>>>(
        Ybf, W_d2, dinv, Hbf, N);                            // Y3'
    agg_kernel<false, false><<<aggBlocks, 256, 0, stream>>>(
        Hbf, offs, esrc, dinv, b_d2, gout, N);               // out (fp32)
}

// Round 7
// 558.797 us; speedup vs baseline: 2.5345x; 2.5345x over previous
//
#include <hip/hip_runtime.h>
#include <math.h>

// ---------------------------------------------------------------------------
// GCN-VAE fused pipeline for MI355X.
// R6: CSR build rebuilt as a 3-pass counting sort with COALESCED writes only
// (R2/R5 showed scattered 4B stores cost ~9-16x write amplification no
// matter the XCD locality). Aggs reverted to known-good R2 loop shape
// (+ dinv prescale, verified in R5). Matmul/head = R5 (verified).
// ---------------------------------------------------------------------------

__device__ inline float bf2f_lo(unsigned int v) {
    return __uint_as_float(v << 16);
}
__device__ inline float bf2f_hi(unsigned int v) {
    return __uint_as_float(v & 0xFFFF0000u);
}
__device__ inline unsigned short f2bf(float f) {
    unsigned int u = __float_as_uint(f);
    return (unsigned short)((u + 0x7FFFu + ((u >> 16) & 1u)) >> 16);
}
__device__ inline unsigned int get_xcd() {
    unsigned int x;
    asm volatile("s_getreg_b32 %0, hwreg(HW_REG_XCC_ID)" : "=s"(x));
    return x & 7u;
}

__global__ void zero_kernel(int* __restrict__ p, int n) {
    int i = blockIdx.x * blockDim.x + threadIdx.x;
    if (i < n) p[i] = 0;
}

// Pass 1: bucket edges (+self-loops) by dst>>8 into per-(bucket,XCD) slices.
// One 4096-edge tile per block; rank via LDS atomics; writes are ~128B runs
// into this XCD's own slice (single-writer -> full-dirty lines).
__global__ __launch_bounds__(256) void bucketize_kernel(
    const int* __restrict__ src, const int* __restrict__ dst, int E, int N,
    int capS, uint2* __restrict__ pairs, int* __restrict__ gcnt) {
    __shared__ int lcnt[256];
    __shared__ int lbase[256];
    int tid = threadIdx.x;
    int total = E + N;
    int base = blockIdx.x * 4096;
    unsigned int x = get_xcd();
    lcnt[tid] = 0;
    __syncthreads();
    int d[16], s[16], rk[16];
#pragma unroll
    for (int j = 0; j < 16; j++) {
        int idx = base + j * 256 + tid;
        d[j] = -1;
        if (idx < total) {
            if (idx < E) { d[j] = dst[idx]; s[j] = src[idx]; }
            else         { d[j] = idx - E; s[j] = d[j]; }
            rk[j] = atomicAdd(&lcnt[d[j] >> 8], 1);
        }
    }
    __syncthreads();
    if (lcnt[tid] > 0) lbase[tid] = atomicAdd(&gcnt[tid * 8 + (int)x],
                                              lcnt[tid]);
    __syncthreads();
#pragma unroll
    for (int j = 0; j < 16; j++) {
        if (d[j] >= 0) {
            int b = d[j] >> 8;
            int pos = lbase[b] + rk[j];
            if (pos < capS)
                pairs[(size_t)(b * 8 + (int)x) * capS + pos] =
                    make_uint2((unsigned)d[j], (unsigned)s[j]);
        }
    }
}

// Pass 2: scan bucket totals -> bucket bases; offs[N] = grand total.
__global__ __launch_bounds__(256) void scan_bases_kernel(
    const int* __restrict__ gcnt, int nb, int capS, int* __restrict__ bbase,
    int* __restrict__ offs, int N) {
    __shared__ int lds[256];
    int tid = threadIdx.x;
    int t = 0;
    if (tid < nb) {
#pragma unroll
        for (int x = 0; x < 8; x++) {
            int v = gcnt[tid * 8 + x];
            if (v > capS) v = capS;
            t += v;
        }
    }
    lds[tid] = t;
    __syncthreads();
    for (int off = 1; off < 256; off <<= 1) {
        int u = (tid >= off) ? lds[tid - off] : 0;
        __syncthreads();
        lds[tid] += u;
        __syncthreads();
    }
    bbase[tid] = lds[tid] - t;
    if (tid == 255) offs[N] = lds[255];
}

// Pass 3: one block per bucket. LDS counting sort by dst&255, then fully
// coalesced writes of offs/dinv/esrc-segment. No scattered global stores.
__global__ __launch_bounds__(256) void build_kernel(
    const uint2* __restrict__ pairs, const int* __restrict__ gcnt, int capS,
    const int* __restrict__ bbase, int N, int* __restrict__ offs,
    float* __restrict__ dinv, int* __restrict__ esrc) {
    __shared__ int cnt[256];
    __shared__ int loff[256];
    __shared__ int cur[256];
    __shared__ int S[10240];
    int b = blockIdx.x;
    int tid = threadIdx.x;
    cnt[tid] = 0;
    __syncthreads();
    int szx[8];
#pragma unroll
    for (int x = 0; x < 8; x++) {
        int v = gcnt[b * 8 + x];
        if (v > capS) v = capS;
        szx[x] = v;
    }
    // count
#pragma unroll
    for (int x = 0; x < 8; x++) {
        const uint2* bp = pairs + (size_t)(b * 8 + x) * capS;
        for (int i = tid; i < szx[x]; i += 256)
            atomicAdd(&cnt[bp[i].x & 255u], 1);
    }
    __syncthreads();
    int c = cnt[tid];
    loff[tid] = c;
    __syncthreads();
    for (int off = 1; off < 256; off <<= 1) {
        int u = (tid >= off) ? loff[tid - off] : 0;
        __syncthreads();
        loff[tid] += u;
        __syncthreads();
    }
    int excl = loff[tid] - c;
    cur[tid] = excl;
    int total = loff[255];
    int base = bbase[b];
    int d0 = b << 8;
    if (d0 + tid < N) {
        offs[d0 + tid] = base + excl;
        dinv[d0 + tid] = rsqrtf((float)c);   // c >= 1 (self-loop)
    }
    __syncthreads();
    // scatter into LDS (sorted by local dst)
#pragma unroll
    for (int x = 0; x < 8; x++) {
        const uint2* bp = pairs + (size_t)(b * 8 + x) * capS;
        for (int i = tid; i < szx[x]; i += 256) {
            uint2 p = bp[i];
            int pos = atomicAdd(&cur[p.x & 255u], 1);
            if (pos < 10240) S[pos] = (int)p.y;
        }
    }
    __syncthreads();
    if (total > 10240) total = 10240;
    for (int j = tid; j < total; j += 256) esrc[base + j] = S[j];
}

// Tiled matmul: out[N,128] = X[N,K] @ W[K,128], bf16 out. SCALE: multiply
// row r by dinv[r] (prescale for downstream aggregation).
template <int K, bool XBF, bool SCALE>
__global__ __launch_bounds__(256) void matmul_kernel(
    const void* __restrict__ Xv, const float* __restrict__ W,
    const float* __restrict__ dinv, unsigned short* __restrict__ out, int N) {
    const int M = 128;
    __shared__ float ldsW[K][64];
    __shared__ float ldsX[64][K];
    int tid = threadIdx.x;
    int row0 = blockIdx.x * 64;
    int col0 = blockIdx.y * 64;

    for (int i = tid; i < K * 16; i += 256) {
        int k = i >> 4, j4 = i & 15;
        ((float4*)&ldsW[k][0])[j4] =
            *(const float4*)&W[(size_t)k * M + col0 + j4 * 4];
    }
    int maxr = N - row0; if (maxr > 64) maxr = 64;
    if (XBF) {
        const unsigned short* X = (const unsigned short*)Xv;
        for (int i = tid; i < maxr * (K / 8); i += 256) {
            int r = i / (K / 8), c8 = i % (K / 8);
            uint4 u = *(const uint4*)&X[(size_t)(row0 + r) * K + c8 * 8];
            float* dp = &ldsX[r][c8 * 8];
            dp[0] = bf2f_lo(u.x); dp[1] = bf2f_hi(u.x);
            dp[2] = bf2f_lo(u.y); dp[3] = bf2f_hi(u.y);
            dp[4] = bf2f_lo(u.z); dp[5] = bf2f_hi(u.z);
            dp[6] = bf2f_lo(u.w); dp[7] = bf2f_hi(u.w);
        }
    } else {
        const float* X = (const float*)Xv;
        for (int i = tid; i < maxr * (K / 4); i += 256) {
            int r = i / (K / 4), k4 = i % (K / 4);
            ((float4*)&ldsX[r][0])[k4] =
                *(const float4*)&X[(size_t)(row0 + r) * K + k4 * 4];
        }
    }
    __syncthreads();

    int cg = tid & 15, rg = tid >> 4;
    int rbase = rg * 4, cbase = cg * 4;
    float acc[4][4] = {};
    for (int k = 0; k < K; k += 4) {
        float4 xv[4];
#pragma unroll
        for (int r = 0; r < 4; r++)
            xv[r] = *(const float4*)&ldsX[rbase + r][k];
        const float* xp = (const float*)xv;
#pragma unroll
        for (int kk = 0; kk < 4; kk++) {
            float4 wv = *(const float4*)&ldsW[k + kk][cbase];
#pragma unroll
            for (int r = 0; r < 4; r++) {
                float xs = xp[r * 4 + kk];
                acc[r][0] += xs * wv.x;
                acc[r][1] += xs * wv.y;
                acc[r][2] += xs * wv.z;
                acc[r][3] += xs * wv.w;
            }
        }
    }
#pragma unroll
    for (int r = 0; r < 4; r++) {
        int row = row0 + rbase + r;
        if (row < N) {
            float sc = SCALE ? dinv[row] : 1.0f;
            ushort4 o;
            o.x = f2bf(acc[r][0] * sc); o.y = f2bf(acc[r][1] * sc);
            o.z = f2bf(acc[r][2] * sc); o.w = f2bf(acc[r][3] * sc);
            *(ushort4*)&out[(size_t)row * M + col0 + cbase] = o;
        }
    }
}

// Fused VAE head: mean = Ah@Wm+bm, lv = Ah@Wl+bl, z = noise*exp(.5lv)+mean.
// Writes mean/lv/z fp32 (outputs) + zb = dinv*z bf16 (prescaled for W_d1).
__global__ __launch_bounds__(256) void head_kernel(
    const unsigned short* __restrict__ Ah, const float* __restrict__ Wm,
    const float* __restrict__ bm, const float* __restrict__ Wl,
    const float* __restrict__ bl, const float* __restrict__ noise,
    const float* __restrict__ dinv, float* __restrict__ mean,
    float* __restrict__ lv, float* __restrict__ z,
    unsigned short* __restrict__ zb, int N) {
    __shared__ float ldsX[64][128];
    __shared__ float ldsW[128][64];
    int tid = threadIdx.x;
    int row0 = blockIdx.x * 64;
    int maxr = N - row0; if (maxr > 64) maxr = 64;

    for (int i = tid; i < maxr * 16; i += 256) {
        int r = i >> 4, c8 = i & 15;
        uint4 u = *(const uint4*)&Ah[(size_t)(row0 + r) * 128 + c8 * 8];
        float* dp = &ldsX[r][c8 * 8];
        dp[0] = bf2f_lo(u.x); dp[1] = bf2f_hi(u.x);
        dp[2] = bf2f_lo(u.y); dp[3] = bf2f_hi(u.y);
        dp[4] = bf2f_lo(u.z); dp[5] = bf2f_hi(u.z);
        dp[6] = bf2f_lo(u.w); dp[7] = bf2f_hi(u.w);
    }
    for (int i = tid; i < 128 * 16; i += 256) {
        int k = i >> 4, j4 = i & 15;
        ((float4*)&ldsW[k][0])[j4] = ((const float4*)&Wm[(size_t)k * 64])[j4];
    }
    __syncthreads();

    int cg = tid & 15, rg = tid >> 4;
    int rbase = rg * 4, cbase = cg * 4;
    float accM[4][4] = {}, accL[4][4] = {};

    for (int k = 0; k < 128; k += 4) {
        float4 xv[4];
#pragma unroll
        for (int r = 0; r < 4; r++)
            xv[r] = *(const float4*)&ldsX[rbase + r][k];
        const float* xp = (const float*)xv;
#pragma unroll
        for (int kk = 0; kk < 4; kk++) {
            float4 wv = *(const float4*)&ldsW[k + kk][cbase];
#pragma unroll
            for (int r = 0; r < 4; r++) {
                float xs = xp[r * 4 + kk];
                accM[r][0] += xs * wv.x;
                accM[r][1] += xs * wv.y;
                accM[r][2] += xs * wv.z;
                accM[r][3] += xs * wv.w;
            }
        }
    }
    __syncthreads();
    for (int i = tid; i < 128 * 16; i += 256) {
        int k = i >> 4, j4 = i & 15;
        ((float4*)&ldsW[k][0])[j4] = ((const float4*)&Wl[(size_t)k * 64])[j4];
    }
    __syncthreads();
    for (int k = 0; k < 128; k += 4) {
        float4 xv[4];
#pragma unroll
        for (int r = 0; r < 4; r++)
            xv[r] = *(const float4*)&ldsX[rbase + r][k];
        const float* xp = (const float*)xv;
#pragma unroll
        for (int kk = 0; kk < 4; kk++) {
            float4 wv = *(const float4*)&ldsW[k + kk][cbase];
#pragma unroll
            for (int r = 0; r < 4; r++) {
                float xs = xp[r * 4 + kk];
                accL[r][0] += xs * wv.x;
                accL[r][1] += xs * wv.y;
                accL[r][2] += xs * wv.z;
                accL[r][3] += xs * wv.w;
            }
        }
    }

    float4 bmv = *(const float4*)&bm[cbase];
    float4 blv = *(const float4*)&bl[cbase];
#pragma unroll
    for (int r = 0; r < 4; r++) {
        int row = row0 + rbase + r;
        if (row < N) {
            float4 m = make_float4(accM[r][0] + bmv.x, accM[r][1] + bmv.y,
                                   accM[r][2] + bmv.z, accM[r][3] + bmv.w);
            float4 l = make_float4(accL[r][0] + blv.x, accL[r][1] + blv.y,
                                   accL[r][2] + blv.z, accL[r][3] + blv.w);
            float4 nv = *(const float4*)&noise[(size_t)row * 64 + cbase];
            float4 zv = make_float4(nv.x * expf(0.5f * l.x) + m.x,
                                    nv.y * expf(0.5f * l.y) + m.y,
                                    nv.z * expf(0.5f * l.z) + m.z,
                                    nv.w * expf(0.5f * l.w) + m.w);
            *(float4*)&mean[(size_t)row * 64 + cbase] = m;
            *(float4*)&lv[(size_t)row * 64 + cbase] = l;
            *(float4*)&z[(size_t)row * 64 + cbase] = zv;
            float sc = dinv[row];
            ushort4 zq;
            zq.x = f2bf(zv.x * sc); zq.y = f2bf(zv.y * sc);
            zq.z = f2bf(zv.z * sc); zq.w = f2bf(zv.w * sc);
            *(ushort4*)&zb[(size_t)row * 64 + cbase] = zq;
        }
    }
}

// Aggregation over dinv-prescaled bf16 rows (R2 loop shape, no per-edge
// weight loads). One wave per dst; lane owns cols {2*lane, 2*lane+1}.
template <bool PRE, bool OUTBF>
__global__ __launch_bounds__(256) void agg_kernel(
    const unsigned short* __restrict__ Y, const int* __restrict__ offsets,
    const int* __restrict__ esrc, const float* __restrict__ dinv,
    const float* __restrict__ bias, void* __restrict__ outv, int N) {
    int wid = (blockIdx.x * blockDim.x + threadIdx.x) >> 6;
    int lane = threadIdx.x & 63;
    if (wid >= N) return;
    int beg = offsets[wid], end = offsets[wid + 1];
    const unsigned int* Yu = (const unsigned int*)Y;  // ushort2 pairs
    float ax = 0.f, ay = 0.f;
    int e = beg;
    for (; e + 4 <= end; e += 4) {
        int s0 = esrc[e], s1 = esrc[e + 1], s2 = esrc[e + 2], s3 = esrc[e + 3];
        unsigned int v0 = Yu[(size_t)s0 * 64 + lane];
        unsigned int v1 = Yu[(size_t)s1 * 64 + lane];
        unsigned int v2 = Yu[(size_t)s2 * 64 + lane];
        unsigned int v3 = Yu[(size_t)s3 * 64 + lane];
        ax += bf2f_lo(v0) + bf2f_lo(v1) + bf2f_lo(v2) + bf2f_lo(v3);
        ay += bf2f_hi(v0) + bf2f_hi(v1) + bf2f_hi(v2) + bf2f_hi(v3);
    }
    for (; e < end; e++) {
        unsigned int v0 = Yu[(size_t)esrc[e] * 64 + lane];
        ax += bf2f_lo(v0);
        ay += bf2f_hi(v0);
    }
    float dd = dinv[wid];
    float rx = ax * dd, ry = ay * dd;
    if (bias) { rx += bias[2 * lane]; ry += bias[2 * lane + 1]; }
    if (PRE) { rx *= dd; ry *= dd; }
    if (OUTBF) {
        unsigned int packed = (unsigned int)f2bf(rx) |
                              ((unsigned int)f2bf(ry) << 16);
        ((unsigned int*)outv)[(size_t)wid * 64 + lane] = packed;
    } else {
        ((float2*)outv)[(size_t)wid * 64 + lane] = make_float2(rx, ry);
    }
}

extern "C" void kernel_launch(void* const* d_in, const int* in_sizes, int n_in,
                              void* d_out, int out_size, void* d_ws,
                              size_t ws_size, hipStream_t stream) {
    const float* feature = (const float*)d_in[0];
    const int*   ei      = (const int*)d_in[1];
    const float* noise   = (const float*)d_in[2];
    const float* W_enc   = (const float*)d_in[3];
    const float* b_enc   = (const float*)d_in[4];
    const float* W_mean  = (const float*)d_in[5];
    const float* b_mean  = (const float*)d_in[6];
    const float* W_lv    = (const float*)d_in[7];
    const float* b_lv    = (const float*)d_in[8];
    const float* W_d1    = (const float*)d_in[9];
    const float* b_d1    = (const float*)d_in[10];
    const float* W_d2    = (const float*)d_in[11];
    const float* b_d2    = (const float*)d_in[12];

    int N = in_sizes[0] / 128;
    int E = in_sizes[1] / 2;
    int nb = (N + 255) >> 8;                  // dst buckets (196 for N=50000)

    float* z_out    = (float*)d_out;
    float* mean_out = z_out + (size_t)N * 64;
    float* lv_out   = z_out + (size_t)N * 128;
    float* gout     = z_out + (size_t)N * 192;

    char* ws = (char*)d_ws;
    unsigned short* Ybf = (unsigned short*)ws; ws += (size_t)N * 128 * 2;
    unsigned short* Hbf = (unsigned short*)ws; ws += (size_t)N * 128 * 2;
    unsigned short* Zbf = (unsigned short*)ws; ws += (size_t)N * 64 * 2;
    int*   esrc  = (int*)ws;   ws += (size_t)(E + N) * 4;
    int*   offs  = (int*)ws;   ws += (size_t)(N + 1) * 4;
    float* dinv  = (float*)ws; ws += (size_t)N * 4;
    int*   gcnt  = (int*)ws;   ws += 256 * 8 * 4;
    int*   bbase = (int*)ws;   ws += 256 * 4;

    // `pairs` ALIASES Ybf+Hbf (CSR build completes before matmuls touch Ybf).
    uint2* pairs = (uint2*)Ybf;
    size_t pairRegion = (size_t)N * 128 * 2 * 2;          // Ybf+Hbf bytes
    int capS = 1536;                                      // per-(bucket,XCD)
    int capMax = (int)(pairRegion / (256 * 8 * sizeof(uint2)));
    if (capS > capMax) capS = capMax;

    const int* src = ei;
    const int* dst = ei + E;
    int total = E + N;

    // ---- CSR build (coalesced counting sort) ----
    zero_kernel<<<(256 * 8 + 255) / 256, 256, 0, stream>>>(gcnt, 256 * 8);
    bucketize_kernel<<<(total + 4095) / 4096, 256, 0, stream>>>(
        src, dst, E, N, capS, pairs, gcnt);
    scan_bases_kernel<<<1, 256, 0, stream>>>(gcnt, nb, capS, bbase, offs, N);
    build_kernel<<<nb, 256, 0, stream>>>(pairs, gcnt, capS, bbase, N, offs,
                                         dinv, esrc);

    int gx = (N + 63) / 64;
    int aggBlocks = (int)(((size_t)N * 64 + 255) / 256);

    // ---- encoder ----
    matmul_kernel<128, false, true><<<dim3(gx, 2), 256, 0, stream>>>(
        feature, W_enc, dinv, Ybf, N);                       // Y1' = dinv*X@We
    agg_kernel<true, true><<<aggBlocks, 256, 0, stream>>>(
        Ybf, offs, esrc, dinv, b_enc, Hbf, N);               // h' = dinv*h
    agg_kernel<false, true><<<aggBlocks, 256, 0, stream>>>(
        Hbf, offs, esrc, dinv, nullptr, Ybf, N);             // Ah
    head_kernel<<<gx, 256, 0, stream>>>(Ybf, W_mean, b_mean, W_lv, b_lv,
                                        noise, dinv, mean_out, lv_out, z_out,
                                        Zbf, N);             // + zb = dinv*z

    // ---- decoder ----
    matmul_kernel<64, true, false><<<dim3(gx, 2), 256, 0, stream>>>(
        Zbf, W_d1, dinv, Hbf, N);                            // Y2' = dinv*z@Wd1
    agg_kernel<true, true><<<aggBlocks, 256, 0, stream>>>(
        Hbf, offs, esrc, dinv, b_d1, Ybf, N);                // hd' = dinv*hd
    matmul_kernel<128, true, false><<<dim3(gx, 2), 256, 0, stream>>>(
        Ybf, W_d2, dinv, Hbf, N);                            // Y3'
    agg_kernel<false, false><<<aggBlocks, 256, 0, stream>>>(
        Hbf, offs, esrc, dinv, b_d2, gout, N);               // out (fp32)
}